// Round 7
// baseline (1009.699 us; speedup 1.0000x reference)
//
#include <hip/hip_runtime.h>
#include <hip/hip_bf16.h>
#include <stdint.h>

#define T_TOK 4096
#define HID   2048
#define FFN_D 4096
#define NE    8
#define PADB  256     // expert padding granularity = BM of the 8-wave GEMM

typedef __attribute__((ext_vector_type(8))) short  short8;
typedef __attribute__((ext_vector_type(4))) float  f32x4;
typedef __attribute__((ext_vector_type(4))) unsigned short u16x4;
typedef unsigned short u16;

__device__ __forceinline__ u16 f2bf(float f) {
    unsigned u = __float_as_uint(f);
    u += 0x7FFFu + ((u >> 16) & 1u);   // RNE
    return (u16)(u >> 16);
}
__device__ __forceinline__ float bf2f(u16 v) {
    return __uint_as_float(((unsigned)v) << 16);
}

// 8 fp32 -> 8 bf16 (RNE, matches f2bf) via v_cvt_pk_bf16_f32 (m240: no builtin)
__device__ __forceinline__ short8 cvt8(f32x4 a, f32x4 b) {
    union { unsigned u[4]; short8 s; } r;
    asm("v_cvt_pk_bf16_f32 %0, %1, %2" : "=v"(r.u[0]) : "v"(a[0]), "v"(a[1]));
    asm("v_cvt_pk_bf16_f32 %0, %1, %2" : "=v"(r.u[1]) : "v"(a[2]), "v"(a[3]));
    asm("v_cvt_pk_bf16_f32 %0, %1, %2" : "=v"(r.u[2]) : "v"(b[0]), "v"(b[1]));
    asm("v_cvt_pk_bf16_f32 %0, %1, %2" : "=v"(r.u[3]) : "v"(b[2]), "v"(b[3]));
    return r.s;
}

// direct global->LDS, 16B per lane; LDS dest = wave-uniform base + lane*16
#define GLD16(g, l) __builtin_amdgcn_global_load_lds( \
    (const __attribute__((address_space(1))) unsigned int*)(g), \
    (__attribute__((address_space(3))) unsigned int*)(l), 16, 0, 0)

// ---------------- fp32 -> bf16 converter (x only now) ----------------
__global__ void k_convert(const float* __restrict__ s, u16* __restrict__ d, long n8) {
    for (long i = (long)blockIdx.x * 256 + threadIdx.x; i < n8; i += (long)gridDim.x * 256) {
        f32x4 a = *((const f32x4*)s + i * 2);
        f32x4 b = *((const f32x4*)s + i * 2 + 1);
        short8 o;
#pragma unroll
        for (int q = 0; q < 4; ++q) { o[q] = (short)f2bf(a[q]); o[q + 4] = (short)f2bf(b[q]); }
        *(short8*)(d + i * 8) = o;
    }
}

// ---------------- router (1 wave per token) ----------------
__global__ void k_router(const float* __restrict__ x, const float* __restrict__ wr,
                         int* __restrict__ topk_id, float* __restrict__ topk_w,
                         int* __restrict__ counts) {
    int lane = threadIdx.x & 63;
    int t = blockIdx.x * 4 + (threadIdx.x >> 6);
    const float* xr = x + (size_t)t * HID;
    float acc[8];
#pragma unroll
    for (int e = 0; e < 8; ++e) acc[e] = 0.f;
    for (int h = lane; h < HID; h += 64) {
        float xv = xr[h];
        f32x4 w0 = *(const f32x4*)(wr + h * 8);
        f32x4 w1 = *(const f32x4*)(wr + h * 8 + 4);
#pragma unroll
        for (int q = 0; q < 4; ++q) { acc[q] += xv * w0[q]; acc[4 + q] += xv * w1[q]; }
    }
#pragma unroll
    for (int e = 0; e < 8; ++e) {
        float v = acc[e];
#pragma unroll
        for (int s = 32; s > 0; s >>= 1) v += __shfl_xor(v, s);
        acc[e] = v;
    }
    if (lane == 0) {
        int i0 = 0; float l0 = acc[0];
#pragma unroll
        for (int e = 1; e < 8; ++e) if (acc[e] > l0) { l0 = acc[e]; i0 = e; }
        int i1 = -1; float l1 = -3.4e38f;
#pragma unroll
        for (int e = 0; e < 8; ++e) if (e != i0 && acc[e] > l1) { l1 = acc[e]; i1 = e; }
        float wA = 1.f / (1.f + expf(l1 - l0));   // top-2 softmax renorm, denom cancels
        topk_id[t * 2] = i0;  topk_id[t * 2 + 1] = i1;
        topk_w[t * 2] = wA;   topk_w[t * 2 + 1] = 1.f - wA;
        atomicAdd(&counts[i0], 1);
        atomicAdd(&counts[i1], 1);
    }
}

// ---------------- padded scan + fill (pad to 256) ----------------
__global__ void k_scan(const int* __restrict__ counts, int* __restrict__ pad_off,
                       int* __restrict__ perm_tok) {
    __shared__ int sTot;
    if (threadIdx.x == 0) {
        int o = 0;
#pragma unroll
        for (int e = 0; e < 8; ++e) { pad_off[e] = o; o += ((counts[e] + PADB - 1) / PADB) * PADB; }
        pad_off[8] = o; sTot = o;
    }
    __syncthreads();
    int tot = sTot;
    for (int i = threadIdx.x; i < tot; i += 256) perm_tok[i] = 0;  // filler = token 0
}

// ---------------- scatter tokens into expert lists ----------------
__global__ void k_scatter(const int* __restrict__ topk_id, int* __restrict__ cursors,
                          const int* __restrict__ pad_off, int* __restrict__ perm_tok,
                          int* __restrict__ pos_of) {
    int t = blockIdx.x * 256 + threadIdx.x;
    if (t >= T_TOK) return;
#pragma unroll
    for (int k = 0; k < 2; ++k) {
        int e = topk_id[t * 2 + k];
        int p = pad_off[e] + atomicAdd(&cursors[e], 1);
        perm_tok[p] = t;
        pos_of[t * 2 + k] = p;
    }
}

// =========== 256-row 8-wave GEMM, fused fp32->bf16 B staging ================
// A [rows,KTOT] bf16 (opt. gathered, via global_load_lds);
// B [NTOT,KTOT] fp32 per expert, reg-staged + v_cvt_pk_bf16_f32 + ds_write
// (T14: loads at tile top, cvt+write after the 4 MFMA phases -> full-tile cover).
// Every wave owns 32 A-rows (4 GLD16) and 32 B-rows (8 dwordx4 + 16 cvt + 4
// ds_write_b128). One vmcnt(0)+lgkmcnt(0)+barrier per K-tile (same sync
// structure as R6). Full 3-bit row-XOR swizzle both-sides (rule 21).
template<int KTOT, int NTOT, bool DUAL, bool GATHER>
__global__ __launch_bounds__(512, 2) void k_gemm8f(
    const u16* __restrict__ A,
    const float* __restrict__ B0all,
    const float* __restrict__ B1all,
    u16* __restrict__ C,
    const int* __restrict__ perm_tok,
    const int* __restrict__ pad_off)
{
    constexpr int BMt   = 256;
    constexpr int BNt   = DUAL ? 128 : 256;
    constexpr int NI    = DUAL ? 2 : 4;
    constexpr int WCW   = DUAL ? 32 : 64;    // wave col width
    constexpr int CPX   = (NTOT / BNt) / 8;
    constexpr int NK    = KTOT / 64;
    constexpr int ATILE = BMt * 64;          // u16 per buffer
    constexpr int BTILE = BNt * 64;          // u16 per matrix per buffer

    const int bid = blockIdx.x;
    const int xcd = bid & 7;
    const int idx = bid >> 3;
    const int m0  = (idx / CPX) * BMt;
    if (m0 >= pad_off[8]) return;
    const int n0  = (xcd * CPX + (idx % CPX)) * BNt;
    int e = 0;
    while (pad_off[e + 1] <= m0) ++e;

    __shared__ u16 As[2 * ATILE];
    __shared__ u16 Bs0[2 * BTILE];
    __shared__ u16 Bs1[DUAL ? 2 * BTILE : 8];
    __shared__ int tokS[GATHER ? BMt : 8];

    const int tid = threadIdx.x;
    const int w = tid >> 6, l = tid & 63;
    if (GATHER) {
        for (int i = tid; i < BMt; i += 512) tokS[i] = perm_tok[m0 + i];
        __syncthreads();
    }

    const float* B0 = B0all + (size_t)e * NTOT * KTOT;
    const float* B1 = DUAL ? (B1all + (size_t)e * NTOT * KTOT) : B0all;

    const int lr = l >> 3;              // row within an 8-row segment
    const int c  = (l & 7) ^ lr;        // inverse-swizzled source chunk (16B bf16 units)

    // ---- A: wave owns rows [w*32, +32): 4 GLD16 per tile ----
    const u16* aSrc[4];
    u16* aDst[4];
#pragma unroll
    for (int ja = 0; ja < 4; ++ja) {
        const int row = w * 32 + ja * 8 + lr;
        const long ar = GATHER ? (long)tokS[row] : (long)(m0 + row);
        aSrc[ja] = A + ar * KTOT + c * 8;
        aDst[ja] = (u16*)As + (w * 32 + ja * 8) * 64;   // wave-uniform base
    }

    // ---- B: wave owns 32 fp32 rows: 8 dwordx4 + 16 cvt_pk + 4 ds_write ----
    const float* Bg = DUAL ? (w < 4 ? B0 : B1) : B0;
    u16* bL = DUAL ? (w < 4 ? (u16*)Bs0 : (u16*)Bs1) : (u16*)Bs0;
    const int bBase = DUAL ? (w & 3) * 32 : w * 32;
    const float* bSrc[4];
    u16* bDst[4];
#pragma unroll
    for (int jb = 0; jb < 4; ++jb) {
        const int rowb = bBase + jb * 8 + lr;
        bSrc[jb] = Bg + (size_t)(n0 + rowb) * KTOT + c * 8;     // float offset: chunk = 8 floats
        bDst[jb] = bL + (bBase + jb * 8) * 64 + l * 8;          // same slot as GLD16 would use
    }

    const int wr = w >> 2, wc = w & 3;
    const int fr = l & 15, fk = l >> 4, x7 = l & 7;
    const int pc0 = ((fk ^ x7) << 3);
    const int pc1 = pc0 ^ 32;
    const int aB = (wr * 128 + fr) * 64;
    const int bB = (wc * WCW + fr) * 64;

    f32x4 acc0[8][NI], acc1[8][NI];
    const f32x4 fz = {0.f, 0.f, 0.f, 0.f};
#pragma unroll
    for (int mi = 0; mi < 8; ++mi)
#pragma unroll
        for (int ni = 0; ni < NI; ++ni) { acc0[mi][ni] = fz; if (DUAL) acc1[mi][ni] = fz; }

    f32x4 br[8];

    // prologue: stage tile 0 into buffer 0
#pragma unroll
    for (int jb = 0; jb < 4; ++jb) {
        br[2 * jb]     = ((const f32x4*)bSrc[jb])[0];
        br[2 * jb + 1] = ((const f32x4*)bSrc[jb])[1];
    }
#pragma unroll
    for (int ja = 0; ja < 4; ++ja) GLD16(aSrc[ja], aDst[ja]);
#pragma unroll
    for (int jb = 0; jb < 4; ++jb)
        *(short8*)(bDst[jb]) = cvt8(br[2 * jb], br[2 * jb + 1]);
    asm volatile("s_waitcnt vmcnt(0) lgkmcnt(0)" ::: "memory");
    __builtin_amdgcn_s_barrier();
    __builtin_amdgcn_sched_barrier(0);

#pragma unroll 1
    for (int t = 0; t < NK; ++t) {
        const int cb = t & 1, nb = cb ^ 1;
        const long kE = (long)(t + 1) * 64;
        const bool hasNext = (t + 1 < NK);
        const u16* aC  = (const u16*)As  + cb * ATILE;
        const u16* b0C = (const u16*)Bs0 + cb * BTILE;
        const u16* b1C = (const u16*)Bs1 + (DUAL ? cb * BTILE : 0);

        // ---- stage issues for tile t+1 (full-tile latency cover) ----
        if (hasNext) {
#pragma unroll
            for (int jb = 0; jb < 4; ++jb) {
                const f32x4* p = (const f32x4*)(bSrc[jb] + kE);
                br[2 * jb]     = p[0];
                br[2 * jb + 1] = p[1];
            }
#pragma unroll
            for (int ja = 0; ja < 4; ++ja) GLD16(aSrc[ja] + kE, aDst[ja] + nb * ATILE);
        }
        __builtin_amdgcn_sched_barrier(0);

        short8 af[4], b0f[NI], b1f[NI];

        // ---- P0: mi0-3 x kk0 ----
#pragma unroll
        for (int mi = 0; mi < 4; ++mi) af[mi] = *(const short8*)(aC + aB + mi * 1024 + pc0);
#pragma unroll
        for (int ni = 0; ni < NI; ++ni) {
            b0f[ni] = *(const short8*)(b0C + bB + ni * 1024 + pc0);
            if (DUAL) b1f[ni] = *(const short8*)(b1C + bB + ni * 1024 + pc0);
        }
        __builtin_amdgcn_s_setprio(1);
#pragma unroll
        for (int mi = 0; mi < 4; ++mi)
#pragma unroll
            for (int ni = 0; ni < NI; ++ni) {
                acc0[mi][ni] = __builtin_amdgcn_mfma_f32_16x16x32_bf16(af[mi], b0f[ni], acc0[mi][ni], 0, 0, 0);
                if (DUAL)
                    acc1[mi][ni] = __builtin_amdgcn_mfma_f32_16x16x32_bf16(af[mi], b1f[ni], acc1[mi][ni], 0, 0, 0);
            }
        __builtin_amdgcn_s_setprio(0);

        // ---- P1: mi4-7 x kk0 ----
#pragma unroll
        for (int mi = 0; mi < 4; ++mi) af[mi] = *(const short8*)(aC + aB + (mi + 4) * 1024 + pc0);
        __builtin_amdgcn_s_setprio(1);
#pragma unroll
        for (int mi = 0; mi < 4; ++mi)
#pragma unroll
            for (int ni = 0; ni < NI; ++ni) {
                acc0[mi + 4][ni] = __builtin_amdgcn_mfma_f32_16x16x32_bf16(af[mi], b0f[ni], acc0[mi + 4][ni], 0, 0, 0);
                if (DUAL)
                    acc1[mi + 4][ni] = __builtin_amdgcn_mfma_f32_16x16x32_bf16(af[mi], b1f[ni], acc1[mi + 4][ni], 0, 0, 0);
            }
        __builtin_amdgcn_s_setprio(0);

        // ---- P2: mi0-3 x kk1 ----
#pragma unroll
        for (int mi = 0; mi < 4; ++mi) af[mi] = *(const short8*)(aC + aB + mi * 1024 + pc1);
#pragma unroll
        for (int ni = 0; ni < NI; ++ni) {
            b0f[ni] = *(const short8*)(b0C + bB + ni * 1024 + pc1);
            if (DUAL) b1f[ni] = *(const short8*)(b1C + bB + ni * 1024 + pc1);
        }
        __builtin_amdgcn_s_setprio(1);
#pragma unroll
        for (int mi = 0; mi < 4; ++mi)
#pragma unroll
            for (int ni = 0; ni < NI; ++ni) {
                acc0[mi][ni] = __builtin_amdgcn_mfma_f32_16x16x32_bf16(af[mi], b0f[ni], acc0[mi][ni], 0, 0, 0);
                if (DUAL)
                    acc1[mi][ni] = __builtin_amdgcn_mfma_f32_16x16x32_bf16(af[mi], b1f[ni], acc1[mi][ni], 0, 0, 0);
            }
        __builtin_amdgcn_s_setprio(0);

        // ---- P3: mi4-7 x kk1 ----
#pragma unroll
        for (int mi = 0; mi < 4; ++mi) af[mi] = *(const short8*)(aC + aB + (mi + 4) * 1024 + pc1);
        __builtin_amdgcn_s_setprio(1);
#pragma unroll
        for (int mi = 0; mi < 4; ++mi)
#pragma unroll
            for (int ni = 0; ni < NI; ++ni) {
                acc0[mi + 4][ni] = __builtin_amdgcn_mfma_f32_16x16x32_bf16(af[mi], b0f[ni], acc0[mi + 4][ni], 0, 0, 0);
                if (DUAL)
                    acc1[mi + 4][ni] = __builtin_amdgcn_mfma_f32_16x16x32_bf16(af[mi], b1f[ni], acc1[mi + 4][ni], 0, 0, 0);
            }
        __builtin_amdgcn_s_setprio(0);
        __builtin_amdgcn_sched_barrier(0);

        // ---- cvt+write B(t+1) into nb (regs landed; loads are a tile old) ----
        if (hasNext) {
#pragma unroll
            for (int jb = 0; jb < 4; ++jb)
                *(short8*)(bDst[jb] + nb * BTILE) = cvt8(br[2 * jb], br[2 * jb + 1]);
        }

        // ---- tile boundary: publish nb ----
        asm volatile("s_waitcnt vmcnt(0) lgkmcnt(0)" ::: "memory");
        __builtin_amdgcn_s_barrier();
        __builtin_amdgcn_sched_barrier(0);
    }

    // epilogue: C/D layout col=lane&15, row=(lane>>4)*4+reg; DUAL -> SwiGLU
    const int er = (l >> 4) * 4;
    const int ec = l & 15;
#pragma unroll
    for (int mi = 0; mi < 8; ++mi)
#pragma unroll
        for (int ni = 0; ni < NI; ++ni)
#pragma unroll
            for (int r = 0; r < 4; ++r) {
                size_t prow = (size_t)(m0 + wr * 128 + mi * 16 + er + r);
                int col = n0 + wc * WCW + ni * 16 + ec;
                float v = acc0[mi][ni][r];
                float res;
                if (DUAL) {
                    float g3 = acc1[mi][ni][r];
                    res = v / (1.f + __expf(-v)) * g3;   // silu(g1)*g3
                } else {
                    res = v;
                }
                C[prow * NTOT + col] = f2bf(res);
            }
}

// ---------------- weighted combine ----------------
__global__ void k_combine(const u16* __restrict__ y, const int* __restrict__ pos_of,
                          const float* __restrict__ topk_w, float* __restrict__ out) {
    int idx = blockIdx.x * 256 + threadIdx.x;    // exactly T * (H/4)
    int t  = idx >> 9;
    int c4 = (idx & 511) << 2;
    int p0 = pos_of[t * 2], p1 = pos_of[t * 2 + 1];
    float w0 = topk_w[t * 2], w1 = topk_w[t * 2 + 1];
    u16x4 a = *(const u16x4*)(y + (size_t)p0 * HID + c4);
    u16x4 b = *(const u16x4*)(y + (size_t)p1 * HID + c4);
    f32x4 o;
#pragma unroll
    for (int q = 0; q < 4; ++q) o[q] = w0 * bf2f(a[q]) + w1 * bf2f(b[q]);
    *(f32x4*)(out + (size_t)t * HID + c4) = o;
    if (idx == 0) out[(size_t)T_TOK * HID] = 0.f;   // second output: zeros((1,))
}

__global__ void k_init(int* __restrict__ c) {
    if (threadIdx.x < 16) c[threadIdx.x] = 0;       // counts[8] + cursors[8]
}

extern "C" void kernel_launch(void* const* d_in, const int* in_sizes, int n_in,
                              void* d_out, int out_size, void* d_ws, size_t ws_size,
                              hipStream_t stream) {
    const float* x  = (const float*)d_in[0];
    const float* wr = (const float*)d_in[1];
    const float* w1 = (const float*)d_in[2];
    const float* w2 = (const float*)d_in[3];
    const float* w3 = (const float*)d_in[4];
    float* out = (float*)d_out;
    char* ws = (char*)d_ws;

    // workspace layout (~143 MB)
    u16*  xb  = (u16*)(ws);                          // 16,777,216  (4096 x 2048 bf16)
    u16*  hb  = (u16*)(ws + 16777216);               // 83,886,080  (10240 x 4096 bf16)
    u16*  yb  = (u16*)(ws + 100663296);              // 41,943,040  (10240 x 2048 bf16)
    int*  perm_tok = (int*)(ws + 142606336);         // 10240 ints
    int*  pos_of   = (int*)(ws + 142647296);         // 8192 ints
    int*  topk_id  = (int*)(ws + 142680064);         // 8192 ints
    float* topk_w  = (float*)(ws + 142712832);       // 8192 floats
    int*  cnt      = (int*)(ws + 142745600);         // counts[8]+cursors[8]+pad_off[9]
    int*  counts   = cnt;
    int*  cursors  = cnt + 8;
    int*  pad_off  = cnt + 16;

    k_init<<<1, 64, 0, stream>>>(cnt);
    k_convert<<<2048, 256, 0, stream>>>(x, xb, (long)T_TOK * HID / 8);
    k_router<<<1024, 256, 0, stream>>>(x, wr, topk_id, topk_w, counts);
    k_scan<<<1, 256, 0, stream>>>(counts, pad_off, perm_tok);
    k_scatter<<<16, 256, 0, stream>>>(topk_id, cursors, pad_off, perm_tok, pos_of);

    // stage 1: h = silu(x@w1^T)*(x@w3^T); dual-B BN=128, fp32 weights staged in-kernel
    k_gemm8f<HID, FFN_D, true, true><<<(FFN_D / 128) * 40, 512, 0, stream>>>(
        xb, w1, w3, hb, perm_tok, pad_off);

    // stage 2: y = h @ w2^T; single-B BN=256, fp32 w2 staged in-kernel
    k_gemm8f<FFN_D, HID, false, false><<<(HID / 256) * 40, 512, 0, stream>>>(
        hb, w2, (const float*)nullptr, yb, perm_tok, pad_off);

    k_combine<<<8192, 256, 0, stream>>>(yb, pos_of, topk_w, out);
}